// Round 1
// baseline (2234.134 us; speedup 1.0000x reference)
//
#include <hip/hip_runtime.h>
#include <hip/hip_bf16.h>
#include <cstdint>
#include <cstddef>

// Problem constants (match setup_inputs)
#define B_ 128
#define T_ 100
#define D_ 2048
#define H_ 1024
#define O_ 20

// ---------------------------------------------------------------------------
// prep: build W2oT[h][o] = Wh2o[o][h] (so o-phase gather reads are contiguous)
//       and zero the nbr_events accumulator region of d_out.
// ---------------------------------------------------------------------------
__global__ __launch_bounds__(256) void prep_kernel(const float* __restrict__ Wh2o,
                                                   float* __restrict__ W2oT,
                                                   float* __restrict__ nbr)
{
    int i = blockIdx.x * 256 + threadIdx.x;
    if (i < H_ * O_) {
        int hh = i / O_;
        int oo = i - hh * O_;
        W2oT[i] = Wh2o[oo * H_ + hh];
    }
    if (i < T_) nbr[i] = 0.0f;
}

// ---------------------------------------------------------------------------
// transpose Wh2h[h][j] -> WT[j][h]  (1024x1024), 32x32 LDS tiles
// so the sparse row-gather in phase2 is coalesced across h.
// ---------------------------------------------------------------------------
__global__ __launch_bounds__(256) void transpose_kernel(const float* __restrict__ A,
                                                        float* __restrict__ AT)
{
    __shared__ float tile[32][33];
    int bx = blockIdx.x * 32, by = blockIdx.y * 32;
    int tx = threadIdx.x, ty = threadIdx.y;  // block (32,8)
#pragma unroll
    for (int i = 0; i < 32; i += 8)
        tile[ty + i][tx] = A[(size_t)(by + ty + i) * H_ + bx + tx];
    __syncthreads();
#pragma unroll
    for (int i = 0; i < 32; i += 8)
        AT[(size_t)(bx + ty + i) * H_ + by + tx] = tile[tx][ty + i];
}

// ---------------------------------------------------------------------------
// Xi = X @ Wi2h^T + (bi2h + bh2h)   [12800x2048]*[2048x1024] fp32
// 128x128x16 tile, 256 threads, 8x8 micro-tile. No fp32 MFMA on CDNA4 ->
// vector FMA GEMM.
// ---------------------------------------------------------------------------
__global__ __launch_bounds__(256) void gemm_xi_kernel(
    const float* __restrict__ X,     // [B*T, D]
    const float* __restrict__ W,     // [H, D]
    const float* __restrict__ bi2h,
    const float* __restrict__ bh2h,
    float* __restrict__ Xi)          // [B*T, H]
{
    constexpr int BM = 128, BN = 128, BK = 16;
    __shared__ float As[BK][BM + 4];
    __shared__ float Bs[BK][BN + 4];
    const int tid = threadIdx.x;
    const int m0 = blockIdx.x * BM;
    const int n0 = blockIdx.y * BN;
    const int tm = tid >> 4;          // 0..15
    const int tn = tid & 15;          // 0..15
    const int ldr = tid >> 2;         // 0..63
    const int ldc = (tid & 3) << 2;   // 0,4,8,12

    float acc[8][8];
#pragma unroll
    for (int i = 0; i < 8; ++i)
#pragma unroll
        for (int j = 0; j < 8; ++j) acc[i][j] = 0.0f;

    for (int k0 = 0; k0 < D_; k0 += BK) {
#pragma unroll
        for (int p = 0; p < 2; ++p) {
            int r = ldr + p * 64;
            float4 v = *(const float4*)(X + (size_t)(m0 + r) * D_ + k0 + ldc);
            As[ldc + 0][r] = v.x; As[ldc + 1][r] = v.y;
            As[ldc + 2][r] = v.z; As[ldc + 3][r] = v.w;
        }
#pragma unroll
        for (int p = 0; p < 2; ++p) {
            int r = ldr + p * 64;
            float4 v = *(const float4*)(W + (size_t)(n0 + r) * D_ + k0 + ldc);
            Bs[ldc + 0][r] = v.x; Bs[ldc + 1][r] = v.y;
            Bs[ldc + 2][r] = v.z; Bs[ldc + 3][r] = v.w;
        }
        __syncthreads();
#pragma unroll
        for (int k = 0; k < BK; ++k) {
            float4 A0 = *(const float4*)&As[k][tm * 8];
            float4 A1 = *(const float4*)&As[k][tm * 8 + 4];
            float4 B0 = *(const float4*)&Bs[k][tn * 8];
            float4 B1 = *(const float4*)&Bs[k][tn * 8 + 4];
            float a[8] = {A0.x, A0.y, A0.z, A0.w, A1.x, A1.y, A1.z, A1.w};
            float bb[8] = {B0.x, B0.y, B0.z, B0.w, B1.x, B1.y, B1.z, B1.w};
#pragma unroll
            for (int i = 0; i < 8; ++i)
#pragma unroll
                for (int j = 0; j < 8; ++j) acc[i][j] += a[i] * bb[j];
        }
        __syncthreads();
    }

    float bsum[8];
#pragma unroll
    for (int j = 0; j < 8; ++j) {
        int n = n0 + tn * 8 + j;
        bsum[j] = bi2h[n] + bh2h[n];
    }
#pragma unroll
    for (int i = 0; i < 8; ++i) {
        size_t row = (size_t)(m0 + tm * 8 + i);
        float4 o0 = {acc[i][0] + bsum[0], acc[i][1] + bsum[1],
                     acc[i][2] + bsum[2], acc[i][3] + bsum[3]};
        float4 o1 = {acc[i][4] + bsum[4], acc[i][5] + bsum[5],
                     acc[i][6] + bsum[6], acc[i][7] + bsum[7]};
        *(float4*)(Xi + row * H_ + n0 + tn * 8)     = o0;
        *(float4*)(Xi + row * H_ + n0 + tn * 8 + 4) = o1;
    }
}

// ---------------------------------------------------------------------------
// phase2: the sequential recurrence. Batch elements are independent ->
// one 1024-thread workgroup per b (thread = hidden neuron h), t-loop inside,
// __syncthreads-only synchronization. Spikes are {0,1}: recurrent matvec =
// sum of WT rows over the active list (ballot-compacted each step).
// Spike history kept as 2x64-bit masks in registers; nbr via exact float
// atomicAdd of integer counts.
// ---------------------------------------------------------------------------
__global__ __launch_bounds__(1024) void phase2_kernel(
    const float* __restrict__ Xi,      // [B*T, H] (includes both biases)
    const float* __restrict__ WT,      // [j*H + h]
    const float* __restrict__ W2oT,    // [h*O + o]
    const float* __restrict__ bh2o,    // [O]
    const float* __restrict__ thr_h_g, // [H]
    const float* __restrict__ thr_o_g, // [O]
    const float* __restrict__ hm0,     // [B,H]
    const float* __restrict__ hs0,     // [B,H]
    const float* __restrict__ om0,     // [B,O]
    ulonglong2* __restrict__ spk,      // [B*H] spike bitmasks (t<64, t>=64)
    float* __restrict__ osum_out,      // [B,O]
    float* __restrict__ nbr_acc)       // [T] pre-zeroed (in d_out)
{
    const int b = blockIdx.x;
    const int h = threadIdx.x;
    const int lane = h & 63;
    const int wv = h >> 6;

    __shared__ int   s_list[H_];
    __shared__ int   s_cnt;
    __shared__ float s_opart[16][O_];
    __shared__ int   s_wpop[16];
    __shared__ float s_om[O_];
    __shared__ float s_osum[O_];
    __shared__ float s_tho[O_];
    __shared__ float s_bo[O_];

    float hm = hm0[(size_t)b * H_ + h];
    const float thr = thr_h_g[h];

    if (h < O_) {
        s_om[h]   = om0[(size_t)b * O_ + h];
        s_osum[h] = 0.0f;
        s_tho[h]  = thr_o_g[h];
        s_bo[h]   = bh2o[h];
    }
    if (h == 0) s_cnt = 0;
    __syncthreads();
    {   // initial active list from hs0 (zeros in practice, handled generally)
        bool act = hs0[(size_t)b * H_ + h] > 0.5f;
        unsigned long long mask = __ballot(act);
        int base = 0;
        if (lane == 0) { int pc = __popcll(mask); if (pc) base = atomicAdd(&s_cnt, pc); }
        base = __shfl(base, 0);
        if (act) s_list[base + __popcll(mask & ((1ull << lane) - 1ull))] = h;
    }
    __syncthreads();

    unsigned long long bits0 = 0, bits1 = 0;
    const float* wtb = WT + h;

    for (int t = 0; t < T_; ++t) {
        // ---- gather: h_in = Xi + sum of active WT rows ----
        float acc = Xi[((size_t)b * T_ + t) * H_ + h];
        int cnt = s_cnt;
        float a0 = 0.f, a1 = 0.f, a2 = 0.f, a3 = 0.f;
        int l = 0;
        for (; l + 4 <= cnt; l += 4) {
            int j0 = s_list[l + 0];
            int j1 = s_list[l + 1];
            int j2 = s_list[l + 2];
            int j3 = s_list[l + 3];
            a0 += wtb[(size_t)j0 << 10];
            a1 += wtb[(size_t)j1 << 10];
            a2 += wtb[(size_t)j2 << 10];
            a3 += wtb[(size_t)j3 << 10];
        }
        for (; l < cnt; ++l) a0 += wtb[(size_t)s_list[l] << 10];
        acc += (a0 + a1) + (a2 + a3);

        // ---- LIF update (exact mem_update semantics) ----
        hm += acc;
        bool sp = (hm - thr) > 0.0f;   // strict >
        if (sp) hm = 0.0f;             // mem*(1-spike)
        if (hm < -thr) hm = -thr;      // clamp
        if (sp) { if (t < 64) bits0 |= (1ull << t); else bits1 |= (1ull << (t - 64)); }

        __syncthreads();               // S1: old list reads done
        if (h == 0) s_cnt = 0;
        __syncthreads();               // S2
        unsigned long long mask = __ballot(sp);
        int pc = __popcll(mask);
        int base = 0;
        if (lane == 0) { s_wpop[wv] = pc; if (pc) base = atomicAdd(&s_cnt, pc); }
        base = __shfl(base, 0);
        if (sp) s_list[base + __popcll(mask & ((1ull << lane) - 1ull))] = h;
        __syncthreads();               // S3: new list + s_wpop ready

        // ---- output layer: o_in[o] = bh2o[o] + sum_{active j} W2oT[j][o] ----
        cnt = s_cnt;
        int per = (cnt + 15) >> 4;
        int lo = wv * per;
        int hi = lo + per; if (hi > cnt) hi = cnt;
        if (lane < O_) {
            float op = 0.0f;
            for (int q = lo; q < hi; ++q) {
                int j = s_list[q];
                op += W2oT[j * O_ + lane];
            }
            s_opart[wv][lane] = op;
        }
        __syncthreads();               // S4

        float osp_local = 0.0f;
        if (h < O_) {
            float oin = s_bo[h];
#pragma unroll
            for (int w = 0; w < 16; ++w) oin += s_opart[w][h];
            float om = s_om[h] + oin;
            float osp = ((om - s_tho[h]) > 0.0f) ? 1.0f : 0.0f;
            if (osp > 0.5f) om = 0.0f;
            if (om < -s_tho[h]) om = -s_tho[h];
            s_om[h] = om;
            s_osum[h] += osp;
            osp_local = osp;
        }
        if (h < 64) {                  // wave 0: reduce output spike count + nbr
            float c = osp_local;
            c += __shfl_xor(c, 1);
            c += __shfl_xor(c, 2);
            c += __shfl_xor(c, 4);
            c += __shfl_xor(c, 8);
            c += __shfl_xor(c, 16);
            c += __shfl_xor(c, 32);
            if (lane == 0) {
                int hidcnt = 0;
#pragma unroll
                for (int w = 0; w < 16; ++w) hidcnt += s_wpop[w];
                // integer-valued floats: atomicAdd is exact & order-independent
                atomicAdd(&nbr_acc[t], c + (float)hidcnt);
            }
        }
        // next-iter gather reads s_list/s_cnt, next writes are after S1/S2: safe
    }

    ulonglong2 vv; vv.x = bits0; vv.y = bits1;
    spk[(size_t)b * H_ + h] = vv;
    if (h < O_) osum_out[(size_t)b * O_ + h] = s_osum[h];
}

// ---------------------------------------------------------------------------
// hidden_spike_filt[b,h,tau] = mean of spikes t=tau..tau+9 (91 windows)
// from the per-(b,h) bitmask; sliding-sum over bits.
// ---------------------------------------------------------------------------
__global__ __launch_bounds__(256) void filt_kernel(const ulonglong2* __restrict__ spk,
                                                   float* __restrict__ outf)
{
    int i = blockIdx.x * 256 + threadIdx.x;   // i = b*H + h
    ulonglong2 v = spk[i];
    float* o = outf + (size_t)i * 91;
    int s = __popcll(v.x & 0x3FFull);         // window t=0..9
    o[0] = (float)s * 0.1f;
#pragma unroll 1
    for (int tau = 1; tau <= 90; ++tau) {
        int ta = tau + 9, tsb = tau - 1;
        int add = (ta < 64) ? (int)((v.x >> ta) & 1ull) : (int)((v.y >> (ta - 64)) & 1ull);
        int sub = (tsb < 64) ? (int)((v.x >> tsb) & 1ull) : (int)((v.y >> (tsb - 64)) & 1ull);
        s += add - sub;
        o[tau] = (float)s * 0.1f;
    }
}

// ---------------------------------------------------------------------------
// final: predictions (argmax, first-index-wins ties), NLL loss on
// log_softmax(osum), and nbr scaling by 1/B.
// ---------------------------------------------------------------------------
__global__ __launch_bounds__(256) void final_kernel(const float* __restrict__ osum,
                                                    const int* __restrict__ labels,
                                                    float* __restrict__ dout)
{
    __shared__ float s_loss[B_];
    int tid = threadIdx.x;
    if (tid < B_) {
        int b = tid;
        float v[O_];
#pragma unroll
        for (int o = 0; o < O_; ++o) v[o] = osum[b * O_ + o];
        float mv = v[0];
        int am = 0;
#pragma unroll
        for (int o = 1; o < O_; ++o)
            if (v[o] > mv) { mv = v[o]; am = o; }   // strict >: first max wins
        float se = 0.0f;
#pragma unroll
        for (int o = 0; o < O_; ++o) se += expf(v[o] - mv);
        float lse = mv + logf(se);
        int lab = labels[b];
        dout[b] = (float)am;
        s_loss[b] = v[lab] - lse;
    }
    if (tid >= 128 && tid < 128 + T_) {
        dout[129 + (tid - 128)] *= (1.0f / (float)B_);  // nbr counts -> /B
    }
    __syncthreads();
    if (tid == 0) {
        float s = 0.0f;
        for (int b = 0; b < B_; ++b) s += s_loss[b];
        dout[128] = -s / (float)B_;
    }
}

// ---------------------------------------------------------------------------
extern "C" void kernel_launch(void* const* d_in, const int* in_sizes, int n_in,
                              void* d_out, int out_size, void* d_ws, size_t ws_size,
                              hipStream_t stream)
{
    const float* input  = (const float*)d_in[0];
    const int*   labels = (const int*)d_in[1];
    const float* hm0    = (const float*)d_in[2];
    const float* hs0    = (const float*)d_in[3];
    const float* om0    = (const float*)d_in[4];
    // d_in[5] output_spike: carried but never read by the reference
    const float* Wi2h   = (const float*)d_in[6];
    const float* bi2h   = (const float*)d_in[7];
    const float* Wh2h   = (const float*)d_in[8];
    const float* bh2h   = (const float*)d_in[9];
    const float* Wh2o   = (const float*)d_in[10];
    const float* bh2o   = (const float*)d_in[11];
    const float* thr_h  = (const float*)d_in[12];
    const float* thr_o  = (const float*)d_in[13];

    float* out  = (float*)d_out;
    float* nbr  = out + 129;   // after predictions[128] + loss[1]
    float* filt = out + 229;   // after nbr[100]

    // workspace layout (bytes), total ~58.8 MB
    char* ws = (char*)d_ws;
    float*      Xi   = (float*)(ws);                   // 12800*1024*4 = 52,428,800
    float*      WT   = (float*)(ws + 52428800);        // 1024*1024*4  =  4,194,304
    float*      W2oT = (float*)(ws + 56623104);        // 1024*20*4    =     81,920
    ulonglong2* spk  = (ulonglong2*)(ws + 56705024);   // 131072*16    =  2,097,152
    float*      osum = (float*)(ws + 58802176);        // 128*20*4     =     10,240

    prep_kernel<<<80, 256, 0, stream>>>(Wh2o, W2oT, nbr);
    transpose_kernel<<<dim3(32, 32), dim3(32, 8), 0, stream>>>(Wh2h, WT);
    gemm_xi_kernel<<<dim3(100, 8), 256, 0, stream>>>(input, Wi2h, bi2h, bh2h, Xi);
    phase2_kernel<<<128, 1024, 0, stream>>>(Xi, WT, W2oT, bh2o, thr_h, thr_o,
                                            hm0, hs0, om0, spk, osum, nbr);
    filt_kernel<<<512, 256, 0, stream>>>(spk, filt);
    final_kernel<<<1, 256, 0, stream>>>(osum, labels, out);
}

// Round 2
// 2056.743 us; speedup vs baseline: 1.0862x; 1.0862x over previous
//
#include <hip/hip_runtime.h>
#include <hip/hip_bf16.h>
#include <cstdint>
#include <cstddef>

#define B_ 128
#define T_ 100
#define D_ 2048
#define H_ 1024
#define O_ 20
#define H2 512

__device__ inline void f4acc(float4& a, const float4 v) {
    a.x += v.x; a.y += v.y; a.z += v.z; a.w += v.w;
}

// ---------------------------------------------------------------------------
// prep: W2oT[h][o] = Wh2o[o][h]; zero nbr accumulators and pair flags.
// ---------------------------------------------------------------------------
__global__ __launch_bounds__(256) void prep_kernel(const float* __restrict__ Wh2o,
                                                   float* __restrict__ W2oT,
                                                   float* __restrict__ nbr,
                                                   int* __restrict__ g_flag)
{
    int i = blockIdx.x * 256 + threadIdx.x;
    if (i < H_ * O_) {
        int hh = i / O_;
        int oo = i - hh * O_;
        W2oT[i] = Wh2o[oo * H_ + hh];
    }
    if (i < T_) nbr[i] = 0.0f;
    if (i < B_ * 2) g_flag[i] = 0;
}

// ---------------------------------------------------------------------------
// transpose Wh2h[h][j] -> WT[j][h]
// ---------------------------------------------------------------------------
__global__ __launch_bounds__(256) void transpose_kernel(const float* __restrict__ A,
                                                        float* __restrict__ AT)
{
    __shared__ float tile[32][33];
    int bx = blockIdx.x * 32, by = blockIdx.y * 32;
    int tx = threadIdx.x, ty = threadIdx.y;  // block (32,8)
#pragma unroll
    for (int i = 0; i < 32; i += 8)
        tile[ty + i][tx] = A[(size_t)(by + ty + i) * H_ + bx + tx];
    __syncthreads();
#pragma unroll
    for (int i = 0; i < 32; i += 8)
        AT[(size_t)(bx + ty + i) * H_ + by + tx] = tile[tx][ty + i];
}

// ---------------------------------------------------------------------------
// Xi = X @ Wi2h^T + (bi2h + bh2h).  128x128x16 tile, 256 threads, 8x8 micro.
// Fragment mapping chosen so both LDS fragment reads are <=2-way (free):
//   tm = ((wave>>1)<<3)|(lane>>3), tn = ((wave&1)<<3)|(lane&7)
// -> 8 distinct 32B addresses per wave per read, banks {0,8,16,24} x2.
// ---------------------------------------------------------------------------
__global__ __launch_bounds__(256) void gemm_xi_kernel(
    const float* __restrict__ X,     // [B*T, D]
    const float* __restrict__ W,     // [H, D]
    const float* __restrict__ bi2h,
    const float* __restrict__ bh2h,
    float* __restrict__ Xi)          // [B*T, H]
{
    constexpr int BM = 128, BN = 128, BK = 16;
    __shared__ float As[BK][BM + 4];
    __shared__ float Bs[BK][BN + 4];
    const int tid = threadIdx.x;
    const int m0 = blockIdx.x * BM;
    const int n0 = blockIdx.y * BN;
    const int wave = tid >> 6;
    const int lane = tid & 63;
    const int tm = ((wave >> 1) << 3) | (lane >> 3);   // 0..15
    const int tn = ((wave & 1) << 3) | (lane & 7);     // 0..15
    const int ldr = tid >> 2;          // 0..63
    const int ldc = (tid & 3) << 2;    // 0,4,8,12

    float acc[8][8];
#pragma unroll
    for (int i = 0; i < 8; ++i)
#pragma unroll
        for (int j = 0; j < 8; ++j) acc[i][j] = 0.0f;

    for (int k0 = 0; k0 < D_; k0 += BK) {
#pragma unroll
        for (int p = 0; p < 2; ++p) {
            int r = ldr + p * 64;
            float4 v = *(const float4*)(X + (size_t)(m0 + r) * D_ + k0 + ldc);
            As[ldc + 0][r] = v.x; As[ldc + 1][r] = v.y;
            As[ldc + 2][r] = v.z; As[ldc + 3][r] = v.w;
        }
#pragma unroll
        for (int p = 0; p < 2; ++p) {
            int r = ldr + p * 64;
            float4 v = *(const float4*)(W + (size_t)(n0 + r) * D_ + k0 + ldc);
            Bs[ldc + 0][r] = v.x; Bs[ldc + 1][r] = v.y;
            Bs[ldc + 2][r] = v.z; Bs[ldc + 3][r] = v.w;
        }
        __syncthreads();
#pragma unroll
        for (int k = 0; k < BK; ++k) {
            float4 A0 = *(const float4*)&As[k][tm * 8];
            float4 A1 = *(const float4*)&As[k][tm * 8 + 4];
            float4 B0 = *(const float4*)&Bs[k][tn * 8];
            float4 B1 = *(const float4*)&Bs[k][tn * 8 + 4];
            float a[8] = {A0.x, A0.y, A0.z, A0.w, A1.x, A1.y, A1.z, A1.w};
            float bb[8] = {B0.x, B0.y, B0.z, B0.w, B1.x, B1.y, B1.z, B1.w};
#pragma unroll
            for (int i = 0; i < 8; ++i)
#pragma unroll
                for (int j = 0; j < 8; ++j) acc[i][j] += a[i] * bb[j];
        }
        __syncthreads();
    }

    float bsum[8];
#pragma unroll
    for (int j = 0; j < 8; ++j) {
        int n = n0 + tn * 8 + j;
        bsum[j] = bi2h[n] + bh2h[n];
    }
#pragma unroll
    for (int i = 0; i < 8; ++i) {
        size_t row = (size_t)(m0 + tm * 8 + i);
        float4 o0 = {acc[i][0] + bsum[0], acc[i][1] + bsum[1],
                     acc[i][2] + bsum[2], acc[i][3] + bsum[3]};
        float4 o1 = {acc[i][4] + bsum[4], acc[i][5] + bsum[5],
                     acc[i][6] + bsum[6], acc[i][7] + bsum[7]};
        *(float4*)(Xi + row * H_ + n0 + tn * 8)     = o0;
        *(float4*)(Xi + row * H_ + n0 + tn * 8 + 4) = o1;
    }
}

// ---------------------------------------------------------------------------
// phase2: recurrence, 2 workgroups per batch (one per 512-neuron half),
// 256 wgs x 512 threads -> all 256 CUs. Pairwise lock-step exchange of
// spike bitmasks + o-layer partials through agent-scope atomics
// (double-buffered by t&1; flag = steps published).
// Gather: 4 groups x 128 threads, float4 (4 columns/thread) from WT rows.
// ---------------------------------------------------------------------------
__global__ __launch_bounds__(512) void phase2_kernel(
    const float* __restrict__ Xi,      // [B*T, H]
    const float* __restrict__ WT,      // [j*H + h]
    const float* __restrict__ W2oT,    // [h*O + o]
    const float* __restrict__ bh2o,
    const float* __restrict__ thr_h_g,
    const float* __restrict__ thr_o_g,
    const float* __restrict__ hm0,
    const float* __restrict__ hs0,
    const float* __restrict__ om0,
    unsigned long long* __restrict__ g_mask,   // [B][2 buf][2 half][8]
    float* __restrict__ g_opart,               // [B][2 buf][2 half][O_]
    int* __restrict__ g_flag,                  // [B][2 half]
    ulonglong2* __restrict__ spk,              // [B*H]
    float* __restrict__ osum_out,              // [B,O]
    float* __restrict__ nbr_acc)               // [T] pre-zeroed
{
    const int pair = blockIdx.x >> 1;
    const int half = blockIdx.x & 1;
    const int b = pair;
    const int tid = threadIdx.x;
    const int lane = tid & 63;
    const int wv = tid >> 6;            // 0..7
    const int h0 = half * H2;
    const int h = h0 + tid;

    __shared__ float s_W2o[H2 * O_];            // 40 KB: this half's W2o rows
    __shared__ int   s_list[H_];                // full active list (global j)
    __shared__ float4 s_red[4][128];            // gather partials
    __shared__ unsigned long long s_mask[16];   // full spike bitmask
    __shared__ float s_opart[8][O_];
    __shared__ float s_popart[O_];
    __shared__ int   s_base[16];
    __shared__ int   s_cnt;
    __shared__ float s_om[O_], s_osum[O_], s_tho[O_], s_bo[O_];

    for (int idx = tid; idx < H2 * O_; idx += 512)
        s_W2o[idx] = W2oT[h0 * O_ + idx];

    float hm = hm0[(size_t)b * H_ + h];
    const float thr = thr_h_g[h];

    if (half == 0 && tid < O_) {
        s_om[tid]   = om0[b * O_ + tid];
        s_osum[tid] = 0.0f;
        s_tho[tid]  = thr_o_g[tid];
        s_bo[tid]   = bh2o[tid];
    }

    // initial full bitmask from hs0 (both halves read directly from global)
    {
        bool a1 = hs0[(size_t)b * H_ + wv * 64 + lane] > 0.5f;
        bool a2 = hs0[(size_t)b * H_ + H2 + wv * 64 + lane] > 0.5f;
        unsigned long long m1 = __ballot(a1), m2 = __ballot(a2);
        if (lane == 0) { s_mask[wv] = m1; s_mask[8 + wv] = m2; }
    }
    __syncthreads();
    if (tid == 0) {
        int a = 0;
#pragma unroll
        for (int w = 0; w < 16; ++w) { s_base[w] = a; a += __popcll(s_mask[w]); }
        s_cnt = a;
    }
    __syncthreads();
    {
        int j = tid; int w = j >> 6; unsigned long long mw = s_mask[w];
        if ((mw >> (j & 63)) & 1ull)
            s_list[s_base[w] + __popcll(mw & ((1ull << (j & 63)) - 1ull))] = j;
        j = tid + H2; w = j >> 6; mw = s_mask[w];
        if ((mw >> (j & 63)) & 1ull)
            s_list[s_base[w] + __popcll(mw & ((1ull << (j & 63)) - 1ull))] = j;
    }
    __syncthreads();

    const float4* __restrict__ wt4 = (const float4*)WT + (h0 >> 2);  // + j*256 + cid
    const int g = tid >> 7;          // list group 0..3
    const int cid = tid & 127;       // float4 column id within half
    unsigned long long bits0 = 0, bits1 = 0;

    for (int t = 0; t < T_; ++t) {
        // ---- gather: this half's 512 columns, rows from full active list ----
        const int cnt = s_cnt;
        float4 a0 = {0,0,0,0}, a1 = {0,0,0,0}, a2 = {0,0,0,0}, a3 = {0,0,0,0};
        int l = g;
        for (; l + 12 < cnt; l += 16) {
            int j0 = s_list[l], j1 = s_list[l + 4], j2 = s_list[l + 8], j3 = s_list[l + 12];
            f4acc(a0, wt4[(size_t)j0 * 256 + cid]);
            f4acc(a1, wt4[(size_t)j1 * 256 + cid]);
            f4acc(a2, wt4[(size_t)j2 * 256 + cid]);
            f4acc(a3, wt4[(size_t)j3 * 256 + cid]);
        }
        for (; l < cnt; l += 4) f4acc(a0, wt4[(size_t)s_list[l] * 256 + cid]);
        f4acc(a0, a1); f4acc(a2, a3); f4acc(a0, a2);
        s_red[g][cid] = a0;
        __syncthreads();                       // (A)

        float val = 0.0f;
        const float* rf = (const float*)s_red;
#pragma unroll
        for (int gg = 0; gg < 4; ++gg) val += rf[gg * 512 + tid];

        // ---- hidden LIF ----
        hm += Xi[((size_t)b * T_ + t) * H_ + h] + val;
        bool sp = (hm - thr) > 0.0f;
        if (sp) hm = 0.0f;
        if (hm < -thr) hm = -thr;
        if (sp) { if (t < 64) bits0 |= (1ull << t); else bits1 |= (1ull << (t - 64)); }

        unsigned long long m = __ballot(sp);
        const int myword = half * 8 + wv;
        if (lane == 0) s_mask[myword] = m;

        // ---- own-half o partial: wave wv walks its own ballot word ----
        float op = 0.0f;
        if (lane < O_) {
            unsigned long long mm = m;
            while (mm) {
                int bit = __builtin_ctzll(mm);
                mm &= mm - 1;
                op += s_W2o[(wv * 64 + bit) * O_ + lane];
            }
            s_opart[wv][lane] = op;
        }

        // publish masks (agent-scope, double-buffered)
        const int buf = t & 1;
        unsigned long long* gm = g_mask + (((size_t)(pair * 2 + buf) * 2 + half) * 8);
        if (lane == 0)
            __hip_atomic_store(&gm[wv], m, __ATOMIC_RELAXED, __HIP_MEMORY_SCOPE_AGENT);
        __syncthreads();                       // (B)

        float ownpart = 0.0f;
        if (tid < O_) {
            float s = 0.0f;
#pragma unroll
            for (int w = 0; w < 8; ++w) s += s_opart[w][tid];
            ownpart = s;
            float* go = g_opart + (((size_t)(pair * 2 + buf) * 2 + half) * O_);
            __hip_atomic_store(&go[tid], s, __ATOMIC_RELAXED, __HIP_MEMORY_SCOPE_AGENT);
        }
        __syncthreads();                       // (C) all publishes drained
        if (tid == 0) {
            __hip_atomic_store(&g_flag[pair * 2 + half], t + 1,
                               __ATOMIC_RELEASE, __HIP_MEMORY_SCOPE_AGENT);
            while (__hip_atomic_load(&g_flag[pair * 2 + (half ^ 1)],
                                     __ATOMIC_ACQUIRE, __HIP_MEMORY_SCOPE_AGENT) < t + 1)
                __builtin_amdgcn_s_sleep(1);
        }
        __syncthreads();                       // (D) partner published step t

        const unsigned long long* pm =
            g_mask + (((size_t)(pair * 2 + buf) * 2 + (half ^ 1)) * 8);
        if (tid < 8)
            s_mask[(half ^ 1) * 8 + tid] =
                __hip_atomic_load(&pm[tid], __ATOMIC_RELAXED, __HIP_MEMORY_SCOPE_AGENT);
        if (half == 0 && tid < O_) {
            const float* po = g_opart + (((size_t)(pair * 2 + buf) * 2 + 1) * O_);
            s_popart[tid] =
                __hip_atomic_load(&po[tid], __ATOMIC_RELAXED, __HIP_MEMORY_SCOPE_AGENT);
        }
        __syncthreads();                       // (E)

        // ---- output LIF + nbr (wg half 0 only) ----
        if (half == 0) {
            float osp_l = 0.0f;
            if (tid < O_) {
                float oin = s_bo[tid] + ownpart + s_popart[tid];
                float om = s_om[tid] + oin;
                float osp = ((om - s_tho[tid]) > 0.0f) ? 1.0f : 0.0f;
                if (osp > 0.5f) om = 0.0f;
                if (om < -s_tho[tid]) om = -s_tho[tid];
                s_om[tid] = om;
                s_osum[tid] += osp;
                osp_l = osp;
            }
            if (wv == 0) {
                float c = osp_l;
                c += __shfl_xor(c, 1);  c += __shfl_xor(c, 2);
                c += __shfl_xor(c, 4);  c += __shfl_xor(c, 8);
                c += __shfl_xor(c, 16); c += __shfl_xor(c, 32);
                if (lane == 0) {
                    int hc = 0;
#pragma unroll
                    for (int w = 0; w < 16; ++w) hc += __popcll(s_mask[w]);
                    atomicAdd(&nbr_acc[t], c + (float)hc);  // exact: integer-valued
                }
            }
        }

        // ---- build full active list for next step ----
        if (tid == 0) {
            int a = 0;
#pragma unroll
            for (int w = 0; w < 16; ++w) { s_base[w] = a; a += __popcll(s_mask[w]); }
            s_cnt = a;
        }
        __syncthreads();                       // (G)
        {
            int j = tid; int w = j >> 6; unsigned long long mw = s_mask[w];
            if ((mw >> (j & 63)) & 1ull)
                s_list[s_base[w] + __popcll(mw & ((1ull << (j & 63)) - 1ull))] = j;
            j = tid + H2; w = j >> 6; mw = s_mask[w];
            if ((mw >> (j & 63)) & 1ull)
                s_list[s_base[w] + __popcll(mw & ((1ull << (j & 63)) - 1ull))] = j;
        }
        __syncthreads();                       // (H)
    }

    ulonglong2 vv; vv.x = bits0; vv.y = bits1;
    spk[(size_t)b * H_ + h] = vv;
    if (half == 0 && tid < O_) osum_out[b * O_ + tid] = s_osum[tid];
}

// ---------------------------------------------------------------------------
// sliding-window mean of spike bitmasks
// ---------------------------------------------------------------------------
__global__ __launch_bounds__(256) void filt_kernel(const ulonglong2* __restrict__ spk,
                                                   float* __restrict__ outf)
{
    int i = blockIdx.x * 256 + threadIdx.x;
    ulonglong2 v = spk[i];
    float* o = outf + (size_t)i * 91;
    int s = __popcll(v.x & 0x3FFull);
    o[0] = (float)s * 0.1f;
#pragma unroll 1
    for (int tau = 1; tau <= 90; ++tau) {
        int ta = tau + 9, tsb = tau - 1;
        int add = (ta < 64) ? (int)((v.x >> ta) & 1ull) : (int)((v.y >> (ta - 64)) & 1ull);
        int sub = (tsb < 64) ? (int)((v.x >> tsb) & 1ull) : (int)((v.y >> (tsb - 64)) & 1ull);
        s += add - sub;
        o[tau] = (float)s * 0.1f;
    }
}

// ---------------------------------------------------------------------------
// predictions / loss / nbr scaling
// ---------------------------------------------------------------------------
__global__ __launch_bounds__(256) void final_kernel(const float* __restrict__ osum,
                                                    const int* __restrict__ labels,
                                                    float* __restrict__ dout)
{
    __shared__ float s_loss[B_];
    int tid = threadIdx.x;
    if (tid < B_) {
        int b = tid;
        float v[O_];
#pragma unroll
        for (int o = 0; o < O_; ++o) v[o] = osum[b * O_ + o];
        float mv = v[0];
        int am = 0;
#pragma unroll
        for (int o = 1; o < O_; ++o)
            if (v[o] > mv) { mv = v[o]; am = o; }
        float se = 0.0f;
#pragma unroll
        for (int o = 0; o < O_; ++o) se += expf(v[o] - mv);
        float lse = mv + logf(se);
        dout[b] = (float)am;
        s_loss[b] = v[labels[b]] - lse;
    }
    if (tid >= 128 && tid < 128 + T_) {
        dout[129 + (tid - 128)] *= (1.0f / (float)B_);
    }
    __syncthreads();
    if (tid == 0) {
        float s = 0.0f;
        for (int b = 0; b < B_; ++b) s += s_loss[b];
        dout[128] = -s / (float)B_;
    }
}

// ---------------------------------------------------------------------------
extern "C" void kernel_launch(void* const* d_in, const int* in_sizes, int n_in,
                              void* d_out, int out_size, void* d_ws, size_t ws_size,
                              hipStream_t stream)
{
    const float* input  = (const float*)d_in[0];
    const int*   labels = (const int*)d_in[1];
    const float* hm0    = (const float*)d_in[2];
    const float* hs0    = (const float*)d_in[3];
    const float* om0    = (const float*)d_in[4];
    const float* Wi2h   = (const float*)d_in[6];
    const float* bi2h   = (const float*)d_in[7];
    const float* Wh2h   = (const float*)d_in[8];
    const float* bh2h   = (const float*)d_in[9];
    const float* Wh2o   = (const float*)d_in[10];
    const float* bh2o   = (const float*)d_in[11];
    const float* thr_h  = (const float*)d_in[12];
    const float* thr_o  = (const float*)d_in[13];

    float* out  = (float*)d_out;
    float* nbr  = out + 129;
    float* filt = out + 229;

    char* ws = (char*)d_ws;
    float*      Xi     = (float*)(ws);                   // 52,428,800
    float*      WT     = (float*)(ws + 52428800);        //  4,194,304
    float*      W2oT   = (float*)(ws + 56623104);        //     81,920
    ulonglong2* spk    = (ulonglong2*)(ws + 56705024);   //  2,097,152
    float*      osum   = (float*)(ws + 58802176);        //     10,240
    unsigned long long* g_mask = (unsigned long long*)(ws + 58812416); // 32,768
    float*      g_opart = (float*)(ws + 58845184);       //     40,960
    int*        g_flag  = (int*)(ws + 58886144);         //      1,024

    prep_kernel<<<80, 256, 0, stream>>>(Wh2o, W2oT, nbr, g_flag);
    transpose_kernel<<<dim3(32, 32), dim3(32, 8), 0, stream>>>(Wh2h, WT);
    gemm_xi_kernel<<<dim3(100, 8), 256, 0, stream>>>(input, Wi2h, bi2h, bh2h, Xi);
    phase2_kernel<<<256, 512, 0, stream>>>(Xi, WT, W2oT, bh2o, thr_h, thr_o,
                                           hm0, hs0, om0, g_mask, g_opart, g_flag,
                                           spk, osum, nbr);
    filt_kernel<<<512, 256, 0, stream>>>(spk, filt);
    final_kernel<<<1, 256, 0, stream>>>(osum, labels, out);
}